// Round 2
// baseline (3050.866 us; speedup 1.0000x reference)
//
#include <hip/hip_runtime.h>
#include <hip/hip_bf16.h>

// ---------------------------------------------------------------------------
// MLXAttention on MI355X — fp32-accurate via fp16 hi/lo split GEMMs.
//
// Pipeline:
//   1. split x  -> A2x  [8192 x 8192] fp16   (cols 0..4095 = hi, 4096.. = lo)
//      split Wq/Wk/Wv/Wo -> B2*              (same layout, N rows)
//   2. q = A2x (*) B2q + bq  via FUSED 3-product MFMA GEMM
//      (hi*hi + hi*lo + lo*hi in ONE K-pass, 48 MFMA per barrier-pair)
//   3. per-token attention: reference's tile-by-4 + softmax32 reduces EXACTLY
//      to softmax over the 8 kv heads. Writes attn as split fp16 into A2x.
//   4. out = A2attn (*) B2o + bo  -> d_out (fp32)
//
// GEMM kernel: 128x128 tile, BK=32, 4 waves (2x2), 16x16x32 f16 MFMA.
//   - fused hi/lo staging: 4 LDS tiles (Ahi,Alo,Bhi,Blo), 8 gload_lds/step
//   - LDS bank-conflict swizzle: global source column permuted per-lane
//     (linear LDS dest, rule #21) + matching involution on ds_read column.
//     write col16' = (lane&3)^((lane>>3)&3); read col16' = (lane>>4)^((rA>>1)&3).
//     Spreads rows 0..7 over all 8 16B-units per 128B -> 2-way (free).
//   - bijective XCD swizzle (grids 2048/512, both %8==0).
//
// ws layout (bytes):            offset        size
//   A2x / A2attn (fp16)         0             134,217,728
//   B2q (fp16)                  134,217,728    67,108,864
//   B2k (fp16)                  201,326,592    16,777,216
//   B2v (fp16)                  218,103,808    16,777,216
//   B2o (fp16)                  234,881,024    67,108,864
//   q (f32)                     301,989,888   134,217,728
//   k (f32)                     436,207,616    33,554,432
//   v (f32)                     469,762,048    33,554,432
//   total                       503,316,480  (~480 MiB required)
// ---------------------------------------------------------------------------

typedef _Float16 half8 __attribute__((ext_vector_type(8)));
typedef _Float16 half4v __attribute__((ext_vector_type(4)));
typedef float floatx4 __attribute__((ext_vector_type(4)));

#define K_DIM 4096
#define LDAB 8192   // row stride (halfs) of split matrices
#define BM 128
#define BN 128
#define BK 32

__device__ __forceinline__ void gload16(const void* g, void* l) {
    __builtin_amdgcn_global_load_lds((const __attribute__((address_space(1))) void*)g,
                                     (__attribute__((address_space(3))) void*)l,
                                     16, 0, 0);
}

// ---------------------------------------------------------------------------
// split fp32 -> (hi, lo) fp16, cols fixed at 4096, dst row stride 8192.
// ---------------------------------------------------------------------------
__global__ void split_f32(const float* __restrict__ src, _Float16* __restrict__ dst,
                          long long rows) {
    long long n4 = rows * 1024;   // float4 count (4096 cols / 4)
    long long stride = (long long)gridDim.x * blockDim.x;
    for (long long i = (long long)blockIdx.x * blockDim.x + threadIdx.x; i < n4; i += stride) {
        float4 v = ((const float4*)src)[i];
        long long r = i >> 10;          // / 1024
        int c = ((int)(i & 1023)) << 2; // *4
        half4v hi, lo;
        hi[0] = (_Float16)v.x; lo[0] = (_Float16)(v.x - (float)hi[0]);
        hi[1] = (_Float16)v.y; lo[1] = (_Float16)(v.y - (float)hi[1]);
        hi[2] = (_Float16)v.z; lo[2] = (_Float16)(v.z - (float)hi[2]);
        hi[3] = (_Float16)v.w; lo[3] = (_Float16)(v.w - (float)hi[3]);
        *(half4v*)&dst[r * LDAB + c] = hi;
        *(half4v*)&dst[r * LDAB + K_DIM + c] = lo;
    }
}

// ---------------------------------------------------------------------------
// C[M,N] = A2 (*) B2^T + bias, 3-product fused.  A2:[M,8192], B2:[N,8192] fp16.
// Grid: x = M/128 (must be 64), y = N/128.
// ---------------------------------------------------------------------------
__global__ __launch_bounds__(256) void gemm_split3_fused(
    const _Float16* __restrict__ A, const _Float16* __restrict__ B,
    float* __restrict__ C, const float* __restrict__ bias, int N) {

    __shared__ __attribute__((aligned(16))) _Float16 lAhi[BM * BK];
    __shared__ __attribute__((aligned(16))) _Float16 lAlo[BM * BK];
    __shared__ __attribute__((aligned(16))) _Float16 lBhi[BN * BK];
    __shared__ __attribute__((aligned(16))) _Float16 lBlo[BN * BK];

    const int tid = threadIdx.x;
    const int lane = tid & 63;
    const int w = tid >> 6;          // wave 0..3
    const int wm = w >> 1;           // wave row (0..1)
    const int wn = w & 1;            // wave col (0..1)

    // bijective XCD swizzle (nwg % 8 == 0 for all our grids)
    const int f = blockIdx.y * 64 + blockIdx.x;
    const int nwg = (int)gridDim.y * 64;
    const int lid = (f & 7) * (nwg >> 3) + (f >> 3);
    const long long brow = (long long)(lid & 63) * BM;
    const long long bcol = (long long)(lid >> 6) * BN;

    floatx4 acc[4][4];
#pragma unroll
    for (int m = 0; m < 4; ++m)
#pragma unroll
        for (int n = 0; n < 4; ++n)
            acc[m][n] = (floatx4){0.f, 0.f, 0.f, 0.f};

    // staging: issue covers 64 rows; wave w rows w*16 + (lane>>2).
    // source column pre-swizzled so linear LDS holds swizzled layout.
    const int lrow = w * 16 + (lane >> 2);
    const int lcolw = (((lane & 3) ^ ((lane >> 3) & 3)) * 8);
    const _Float16* Abase = A + (brow + lrow) * (long long)LDAB + lcolw;
    const _Float16* Bbase = B + (bcol + lrow) * (long long)LDAB + lcolw;
    // wave-uniform LDS dest base (halfs); HW adds lane*16B
    _Float16* lAhw = lAhi + w * 512;
    _Float16* lAlw = lAlo + w * 512;
    _Float16* lBhw = lBhi + w * 512;
    _Float16* lBlw = lBlo + w * 512;

    const int rA = lane & 15;
    // swizzled read column (matching involution): (lane>>4) ^ ((rA>>1)&3)
    const int kcs = (((lane >> 4) ^ ((lane >> 1) & 3)) * 8);

    for (int kt = 0; kt < K_DIM; kt += BK) {
        gload16(Abase + kt, lAhw);
        gload16(Abase + kt + 64 * (long long)LDAB, lAhw + 2048);
        gload16(Abase + K_DIM + kt, lAlw);
        gload16(Abase + K_DIM + kt + 64 * (long long)LDAB, lAlw + 2048);
        gload16(Bbase + kt, lBhw);
        gload16(Bbase + kt + 64 * (long long)LDAB, lBhw + 2048);
        gload16(Bbase + K_DIM + kt, lBlw);
        gload16(Bbase + K_DIM + kt + 64 * (long long)LDAB, lBlw + 2048);
        __syncthreads();   // drains vmcnt -> all 4 tiles ready

        half8 ah[4], bh[4], al[4], bl[4];
#pragma unroll
        for (int m = 0; m < 4; ++m)
            ah[m] = *(const half8*)&lAhi[(wm * 64 + m * 16 + rA) * BK + kcs];
#pragma unroll
        for (int n = 0; n < 4; ++n)
            bh[n] = *(const half8*)&lBhi[(wn * 64 + n * 16 + rA) * BK + kcs];
#pragma unroll
        for (int m = 0; m < 4; ++m)
#pragma unroll
            for (int n = 0; n < 4; ++n)
                acc[m][n] = __builtin_amdgcn_mfma_f32_16x16x32_f16(
                    ah[m], bh[n], acc[m][n], 0, 0, 0);
#pragma unroll
        for (int n = 0; n < 4; ++n)
            bl[n] = *(const half8*)&lBlo[(wn * 64 + n * 16 + rA) * BK + kcs];
#pragma unroll
        for (int m = 0; m < 4; ++m)
#pragma unroll
            for (int n = 0; n < 4; ++n)
                acc[m][n] = __builtin_amdgcn_mfma_f32_16x16x32_f16(
                    ah[m], bl[n], acc[m][n], 0, 0, 0);
#pragma unroll
        for (int m = 0; m < 4; ++m)
            al[m] = *(const half8*)&lAlo[(wm * 64 + m * 16 + rA) * BK + kcs];
#pragma unroll
        for (int m = 0; m < 4; ++m)
#pragma unroll
            for (int n = 0; n < 4; ++n)
                acc[m][n] = __builtin_amdgcn_mfma_f32_16x16x32_f16(
                    al[m], bh[n], acc[m][n], 0, 0, 0);
        __syncthreads();   // protect LDS before next stage
    }

    // epilogue: C/D layout col = lane&15, row = (lane>>4)*4 + reg
    const int crow0 = (lane >> 4) * 4;
    const int ccol = lane & 15;
#pragma unroll
    for (int n = 0; n < 4; ++n) {
        long long col = bcol + wn * 64 + n * 16 + ccol;
        float bv_ = bias[col];
#pragma unroll
        for (int m = 0; m < 4; ++m) {
            long long row = brow + wm * 64 + m * 16 + crow0;
            float* cp = C + row * (long long)N + col;
            cp[0]             = acc[m][n][0] + bv_;
            cp[(long long)N]  = acc[m][n][1] + bv_;
            cp[2LL * N]       = acc[m][n][2] + bv_;
            cp[3LL * N]       = acc[m][n][3] + bv_;
        }
    }
}

// ---------------------------------------------------------------------------
// Per-token attention. Reference tiles k/v x4 over heads then softmaxes over
// 32 scores; duplicated columns reduce exactly to softmax over 8 kv heads.
// One block per token (256 threads). Writes split fp16 rows into A2attn.
// ---------------------------------------------------------------------------
__global__ __launch_bounds__(256) void attn_token(
    const float* __restrict__ q, const float* __restrict__ k,
    const float* __restrict__ v, _Float16* __restrict__ out) {

    const int token = blockIdx.x;
    __shared__ float sQ[32 * 128];
    __shared__ float sK[8 * 128];
    __shared__ float sV[8 * 128];
    __shared__ float sP[32 * 8];

    const int t = threadIdx.x;
    {
        const float4* gq = (const float4*)(q + (long long)token * 4096);
        float4* dq = (float4*)sQ;
        dq[t] = gq[t];
        dq[t + 256] = gq[t + 256];
        dq[t + 512] = gq[t + 512];
        dq[t + 768] = gq[t + 768];
        ((float4*)sK)[t] = ((const float4*)(k + (long long)token * 1024))[t];
        ((float4*)sV)[t] = ((const float4*)(v + (long long)token * 1024))[t];
    }
    __syncthreads();

    // scores: thread t -> head h = t>>3, kv head j = t&7
    const int h = t >> 3, j = t & 7;
    const float* qr = sQ + h * 128;
    const float* kr = sK + j * 128;
    float s = 0.f;
#pragma unroll
    for (int i = 0; i < 128; i += 4)
        s += qr[i] * kr[i] + qr[i + 1] * kr[i + 1] +
             qr[i + 2] * kr[i + 2] + qr[i + 3] * kr[i + 3];
    s *= 0.08838834764831845f;   // 1/sqrt(128)

    // softmax over the 8-lane group (== reference's 32-way over duplicates)
    float mx = s;
    mx = fmaxf(mx, __shfl_xor(mx, 1, 8));
    mx = fmaxf(mx, __shfl_xor(mx, 2, 8));
    mx = fmaxf(mx, __shfl_xor(mx, 4, 8));
    float e = expf(s - mx);
    float sum = e;
    sum += __shfl_xor(sum, 1, 8);
    sum += __shfl_xor(sum, 2, 8);
    sum += __shfl_xor(sum, 4, 8);
    sP[t] = e / sum;
    __syncthreads();

    // PV: thread t -> head t>>3, d range (t&7)*16..+16. Write split fp16.
    float p[8];
#pragma unroll
    for (int jj = 0; jj < 8; ++jj) p[jj] = sP[(t >> 3) * 8 + jj];
    const int d0 = (t & 7) * 16;
    const long long obase = (long long)token * LDAB + (t >> 3) * 128;
#pragma unroll
    for (int dd = 0; dd < 16; ++dd) {
        int d = d0 + dd;
        float a = 0.f;
#pragma unroll
        for (int jj = 0; jj < 8; ++jj) a += p[jj] * sV[jj * 128 + d];
        _Float16 hi = (_Float16)a;
        _Float16 lo = (_Float16)(a - (float)hi);
        out[obase + d] = hi;
        out[obase + K_DIM + d] = lo;
    }
}

// ---------------------------------------------------------------------------
extern "C" void kernel_launch(void* const* d_in, const int* in_sizes, int n_in,
                              void* d_out, int out_size, void* d_ws, size_t ws_size,
                              hipStream_t stream) {
    const float* x  = (const float*)d_in[0];
    const float* Wq = (const float*)d_in[1];
    const float* bq = (const float*)d_in[2];
    const float* Wk = (const float*)d_in[3];
    const float* bk = (const float*)d_in[4];
    const float* Wv = (const float*)d_in[5];
    const float* bv = (const float*)d_in[6];
    const float* Wo = (const float*)d_in[7];
    const float* bo = (const float*)d_in[8];
    float* out = (float*)d_out;

    char* ws = (char*)d_ws;
    _Float16* A2x = (_Float16*)(ws + 0);            // 8192 x 8192, reused for attn
    _Float16* B2q = (_Float16*)(ws + 134217728LL);
    _Float16* B2k = (_Float16*)(ws + 201326592LL);
    _Float16* B2v = (_Float16*)(ws + 218103808LL);
    _Float16* B2o = (_Float16*)(ws + 234881024LL);
    float*    qb  = (float*)(ws + 301989888LL);
    float*    kb  = (float*)(ws + 436207616LL);
    float*    vb  = (float*)(ws + 469762048LL);

    // 1. splits (fp32 -> hi/lo fp16)
    split_f32<<<2048, 256, 0, stream>>>(x,  A2x, 8192);
    split_f32<<<2048, 256, 0, stream>>>(Wq, B2q, 4096);
    split_f32<<<1024, 256, 0, stream>>>(Wk, B2k, 1024);
    split_f32<<<1024, 256, 0, stream>>>(Wv, B2v, 1024);
    split_f32<<<2048, 256, 0, stream>>>(Wo, B2o, 4096);

    // 2. projections (fused 3-product MFMA GEMM)
    gemm_split3_fused<<<dim3(64, 32), 256, 0, stream>>>(A2x, B2q, qb, bq, 4096);
    gemm_split3_fused<<<dim3(64, 8),  256, 0, stream>>>(A2x, B2k, kb, bk, 1024);
    gemm_split3_fused<<<dim3(64, 8),  256, 0, stream>>>(A2x, B2v, vb, bv, 1024);

    // 3. per-token attention -> split fp16 into A2x (reuse)
    attn_token<<<8192, 256, 0, stream>>>(qb, kb, vb, A2x);

    // 4. output projection -> d_out
    gemm_split3_fused<<<dim3(64, 32), 256, 0, stream>>>(A2x, B2o, out, bo, 4096);
}

// Round 3
// 2629.830 us; speedup vs baseline: 1.1601x; 1.1601x over previous
//
#include <hip/hip_runtime.h>
#include <hip/hip_bf16.h>

// ---------------------------------------------------------------------------
// MLXAttention on MI355X — fp32-accurate via fp16 hi/lo split GEMMs.
//
//   1. split x -> A2x [8192 x 8192] fp16 (cols 0..4095 hi, 4096.. lo);
//      split Wq/Wk/Wv/Wo likewise.
//   2. q = A2x (*) B2q + bq ; kv = A2x (*) [B2k;B2v] + [bk;bv]  (fused N=2048)
//      via 3-product MFMA GEMM (hi*hi + hi*lo + lo*hi), 256x256 tile,
//      8 waves, 3-phase K-step schedule with counted-vmcnt double buffer.
//   3. per-token attention (softmax over 8 kv heads == reference's 32-way
//      over x4-tiled duplicates) -> split fp16 into A2x (reused).
//   4. out = A2attn (*) B2o + bo.
//
// GEMM schedule per K-step (BK=32), buffers CUR/NXT (dbuf, 128 KiB LDS):
//   P0: ds_read bh[4],ah[8](CUR)  | stage Ahi/Alo(NXT) | bar | prio1 32xMFMA hh | bar
//   P1: ds_read bl[4](CUR)        | stage Bhi/Blo(NXT) | bar | prio1 32xMFMA hl | bar
//   P2: ds_read al[8](CUR)        |                    | bar | prio1 32xMFMA lh |
//       s_waitcnt vmcnt(0) (asm fence; 8 stage loads spanned 5 barriers) | bar
// LDS swizzle (verified: 0 bank conflicts in r2): linear gload_lds dest +
// pre-swizzled global source col16' = (lane&3)^((lane>>3)&3), ds_read col16'
// = (lane>>4)^((lane>>1)&3)  (both sides, same involution, rule #21).
//
// ws layout (bytes):            offset        size
//   A2x / A2attn (fp16)         0             134,217,728
//   B2q (fp16)                  134,217,728    67,108,864
//   B2k (fp16)                  201,326,592    16,777,216   } contiguous ->
//   B2v (fp16)                  218,103,808    16,777,216   } [2048][8192]
//   B2o (fp16)                  234,881,024    67,108,864
//   q (f32)                     301,989,888   134,217,728
//   kv (f32) [8192][2048]       436,207,616    67,108,864
//   total                       503,316,480  (~480 MiB)
// ---------------------------------------------------------------------------

typedef _Float16 half8 __attribute__((ext_vector_type(8)));
typedef _Float16 half4v __attribute__((ext_vector_type(4)));
typedef float floatx4 __attribute__((ext_vector_type(4)));

#define K_DIM 4096
#define LDAB 8192   // row stride (halfs) of split matrices
#define BM 256
#define BN 256
#define BK 32
#define NSTEP 128   // K_DIM / BK

__device__ __forceinline__ void gload16(const void* g, void* l) {
    __builtin_amdgcn_global_load_lds((const __attribute__((address_space(1))) void*)g,
                                     (__attribute__((address_space(3))) void*)l,
                                     16, 0, 0);
}

// ---------------------------------------------------------------------------
__global__ __launch_bounds__(256) void split_f32(
    const float* __restrict__ src, _Float16* __restrict__ dst, long long rows) {
    long long n4 = rows * 1024;   // float4 count (4096 cols / 4)
    long long stride = (long long)gridDim.x * blockDim.x;
    for (long long i = (long long)blockIdx.x * blockDim.x + threadIdx.x; i < n4; i += stride) {
        float4 v = ((const float4*)src)[i];
        long long r = i >> 10;
        int c = ((int)(i & 1023)) << 2;
        half4v hi, lo;
        hi[0] = (_Float16)v.x; lo[0] = (_Float16)(v.x - (float)hi[0]);
        hi[1] = (_Float16)v.y; lo[1] = (_Float16)(v.y - (float)hi[1]);
        hi[2] = (_Float16)v.z; lo[2] = (_Float16)(v.z - (float)hi[2]);
        hi[3] = (_Float16)v.w; lo[3] = (_Float16)(v.w - (float)hi[3]);
        *(half4v*)&dst[r * LDAB + c] = hi;
        *(half4v*)&dst[r * LDAB + K_DIM + c] = lo;
    }
}

// ---------------------------------------------------------------------------
// C[M,N] = A2 (*) B2^T + bias, fused 3-product.  1-D grid, nwg % 8 == 0.
// bias1 != nullptr => KV mode: cols >= 1024 use bias1[col-1024].
// ---------------------------------------------------------------------------
__global__ __launch_bounds__(512, 2) void gemm_split3_8w(
    const _Float16* __restrict__ A, const _Float16* __restrict__ B,
    float* __restrict__ C, const float* __restrict__ bias0,
    const float* __restrict__ bias1, int N) {

    __shared__ __attribute__((aligned(16))) _Float16 lA[2][2][BM * BK];
    __shared__ __attribute__((aligned(16))) _Float16 lB[2][2][BN * BK];

    const int tid = threadIdx.x;
    const int lane = tid & 63;
    const int w = tid >> 6;          // wave 0..7
    const int wm = w >> 2;           // 0..1 -> 128-row half
    const int wn = w & 3;            // 0..3 -> 64-col quarter

    // chunked XCD swizzle + brow-major-within-bcol panel order
    const int f = blockIdx.x;
    const int nwg = gridDim.x;
    const int lid = (f & 7) * (nwg >> 3) + (f >> 3);
    const long long brow = (long long)(lid & 31) * BM;   // M/BM == 32 always
    const long long bcol = (long long)(lid >> 5) * BN;

    floatx4 acc[8][4];
#pragma unroll
    for (int m = 0; m < 8; ++m)
#pragma unroll
        for (int n = 0; n < 4; ++n)
            acc[m][n] = (floatx4){0.f, 0.f, 0.f, 0.f};

    // staging: issue i covers rows i*128 + w*16 + (lane>>2); swizzled src col
    const int srow = w * 16 + (lane >> 2);
    const int scol = 8 * ((lane & 3) ^ ((lane >> 3) & 3));
    const _Float16* Asrc = A + (brow + srow) * (long long)LDAB + scol;
    const _Float16* Bsrc = B + (bcol + srow) * (long long)LDAB + scol;

    const int rA = lane & 15;
    const int kcs = 8 * ((lane >> 4) ^ ((lane >> 1) & 3));   // swizzled read col

    auto stageA = [&](int NXT, int ktn) {
        gload16(Asrc + ktn, &lA[NXT][0][w * 512]);
        gload16(Asrc + 128 * (long long)LDAB + ktn, &lA[NXT][0][4096 + w * 512]);
        gload16(Asrc + K_DIM + ktn, &lA[NXT][1][w * 512]);
        gload16(Asrc + 128 * (long long)LDAB + K_DIM + ktn, &lA[NXT][1][4096 + w * 512]);
    };
    auto stageB = [&](int NXT, int ktn) {
        gload16(Bsrc + ktn, &lB[NXT][0][w * 512]);
        gload16(Bsrc + 128 * (long long)LDAB + ktn, &lB[NXT][0][4096 + w * 512]);
        gload16(Bsrc + K_DIM + ktn, &lB[NXT][1][w * 512]);
        gload16(Bsrc + 128 * (long long)LDAB + K_DIM + ktn, &lB[NXT][1][4096 + w * 512]);
    };

    // prologue: fill buffer 0
    stageA(0, 0);
    stageB(0, 0);
    asm volatile("s_waitcnt vmcnt(0)" ::: "memory");
    __builtin_amdgcn_s_barrier();

    auto step = [&](int CUR, int NXT, int ktn) {
        half8 ah[8], bh[4];
        // ---- P0: hi*hi ----
#pragma unroll
        for (int n = 0; n < 4; ++n)
            bh[n] = *(const half8*)&lB[CUR][0][(wn * 64 + n * 16 + rA) * BK + kcs];
#pragma unroll
        for (int m = 0; m < 8; ++m)
            ah[m] = *(const half8*)&lA[CUR][0][(wm * 128 + m * 16 + rA) * BK + kcs];
        stageA(NXT, ktn);
        __builtin_amdgcn_s_barrier();
        __builtin_amdgcn_s_setprio(1);
#pragma unroll
        for (int m = 0; m < 8; ++m)
#pragma unroll
            for (int n = 0; n < 4; ++n)
                acc[m][n] = __builtin_amdgcn_mfma_f32_16x16x32_f16(
                    ah[m], bh[n], acc[m][n], 0, 0, 0);
        __builtin_amdgcn_s_setprio(0);
        __builtin_amdgcn_s_barrier();
        // ---- P1: hi*lo ----
        {
            half8 bl[4];
#pragma unroll
            for (int n = 0; n < 4; ++n)
                bl[n] = *(const half8*)&lB[CUR][1][(wn * 64 + n * 16 + rA) * BK + kcs];
            stageB(NXT, ktn);
            __builtin_amdgcn_s_barrier();
            __builtin_amdgcn_s_setprio(1);
#pragma unroll
            for (int m = 0; m < 8; ++m)
#pragma unroll
                for (int n = 0; n < 4; ++n)
                    acc[m][n] = __builtin_amdgcn_mfma_f32_16x16x32_f16(
                        ah[m], bl[n], acc[m][n], 0, 0, 0);
            __builtin_amdgcn_s_setprio(0);
            __builtin_amdgcn_s_barrier();
        }
        // ---- P2: lo*hi ----
        {
            half8 al[8];
#pragma unroll
            for (int m = 0; m < 8; ++m)
                al[m] = *(const half8*)&lA[CUR][1][(wm * 128 + m * 16 + rA) * BK + kcs];
            __builtin_amdgcn_s_barrier();
            __builtin_amdgcn_s_setprio(1);
#pragma unroll
            for (int m = 0; m < 8; ++m)
#pragma unroll
                for (int n = 0; n < 4; ++n)
                    acc[m][n] = __builtin_amdgcn_mfma_f32_16x16x32_f16(
                        al[m], bh[n], acc[m][n], 0, 0, 0);
            __builtin_amdgcn_s_setprio(0);
            // next step's 8 stage loads (issued P0/P1) must land before flip
            asm volatile("s_waitcnt vmcnt(0)" ::: "memory");
            __builtin_amdgcn_s_barrier();
        }
    };

    for (int tt = 0; tt < NSTEP; tt += 2) {
        step(0, 1, (tt + 1) * BK);
        step(1, 0, ((tt + 2) & (NSTEP - 1)) * BK);   // wrap: harmless in-bounds prefetch
    }

    // epilogue: C/D layout col = lane&15, row = (lane>>4)*4 + reg
    const float* bias = (bias1 != nullptr && bcol >= 1024) ? (bias1 - 1024) : bias0;
    const int crow0 = (lane >> 4) * 4;
    const int ccol = lane & 15;
#pragma unroll
    for (int n = 0; n < 4; ++n) {
        long long col = bcol + wn * 64 + n * 16 + ccol;
        float bv_ = bias[col];
#pragma unroll
        for (int m = 0; m < 8; ++m) {
            long long row = brow + wm * 128 + m * 16 + crow0;
            float* cp = C + row * (long long)N + col;
            cp[0]             = acc[m][n][0] + bv_;
            cp[(long long)N]  = acc[m][n][1] + bv_;
            cp[2LL * N]       = acc[m][n][2] + bv_;
            cp[3LL * N]       = acc[m][n][3] + bv_;
        }
    }
}

// ---------------------------------------------------------------------------
// Per-token attention. Reference tiles k/v x4 over heads then softmaxes over
// 32 scores; duplicated columns reduce exactly to softmax over 8 kv heads.
// kv: [8192][2048] f32, cols 0..1023 = K (8 heads x 128), 1024.. = V.
// ---------------------------------------------------------------------------
__global__ __launch_bounds__(256) void attn_token(
    const float* __restrict__ q, const float* __restrict__ kv,
    _Float16* __restrict__ out) {

    const int token = blockIdx.x;
    __shared__ float sQ[32 * 128];
    __shared__ float sK[8 * 128];
    __shared__ float sV[8 * 128];
    __shared__ float sP[32 * 8];

    const int t = threadIdx.x;
    {
        const float4* gq = (const float4*)(q + (long long)token * 4096);
        float4* dq = (float4*)sQ;
        dq[t] = gq[t];
        dq[t + 256] = gq[t + 256];
        dq[t + 512] = gq[t + 512];
        dq[t + 768] = gq[t + 768];
        const float4* gkv = (const float4*)(kv + (long long)token * 2048);
        ((float4*)sK)[t] = gkv[t];
        ((float4*)sV)[t] = gkv[t + 256];
    }
    __syncthreads();

    const int h = t >> 3, j = t & 7;
    const float* qr = sQ + h * 128;
    const float* kr = sK + j * 128;
    float s = 0.f;
#pragma unroll
    for (int i = 0; i < 128; i += 4)
        s += qr[i] * kr[i] + qr[i + 1] * kr[i + 1] +
             qr[i + 2] * kr[i + 2] + qr[i + 3] * kr[i + 3];
    s *= 0.08838834764831845f;   // 1/sqrt(128)

    float mx = s;
    mx = fmaxf(mx, __shfl_xor(mx, 1, 8));
    mx = fmaxf(mx, __shfl_xor(mx, 2, 8));
    mx = fmaxf(mx, __shfl_xor(mx, 4, 8));
    float e = expf(s - mx);
    float sum = e;
    sum += __shfl_xor(sum, 1, 8);
    sum += __shfl_xor(sum, 2, 8);
    sum += __shfl_xor(sum, 4, 8);
    sP[t] = e / sum;
    __syncthreads();

    float p[8];
#pragma unroll
    for (int jj = 0; jj < 8; ++jj) p[jj] = sP[(t >> 3) * 8 + jj];
    const int d0 = (t & 7) * 16;
    const long long obase = (long long)token * LDAB + (t >> 3) * 128;
#pragma unroll
    for (int dd = 0; dd < 16; ++dd) {
        int d = d0 + dd;
        float a = 0.f;
#pragma unroll
        for (int jj = 0; jj < 8; ++jj) a += p[jj] * sV[jj * 128 + d];
        _Float16 hi = (_Float16)a;
        _Float16 lo = (_Float16)(a - (float)hi);
        out[obase + d] = hi;
        out[obase + K_DIM + d] = lo;
    }
}

// ---------------------------------------------------------------------------
extern "C" void kernel_launch(void* const* d_in, const int* in_sizes, int n_in,
                              void* d_out, int out_size, void* d_ws, size_t ws_size,
                              hipStream_t stream) {
    const float* x  = (const float*)d_in[0];
    const float* Wq = (const float*)d_in[1];
    const float* bq = (const float*)d_in[2];
    const float* Wk = (const float*)d_in[3];
    const float* bk = (const float*)d_in[4];
    const float* Wv = (const float*)d_in[5];
    const float* bv = (const float*)d_in[6];
    const float* Wo = (const float*)d_in[7];
    const float* bo = (const float*)d_in[8];
    float* out = (float*)d_out;

    char* ws = (char*)d_ws;
    _Float16* A2x  = (_Float16*)(ws + 0);            // reused for attn output
    _Float16* B2q  = (_Float16*)(ws + 134217728LL);
    _Float16* B2kv = (_Float16*)(ws + 201326592LL);  // B2k then B2v, contiguous
    _Float16* B2v  = (_Float16*)(ws + 218103808LL);
    _Float16* B2o  = (_Float16*)(ws + 234881024LL);
    float*    qb   = (float*)(ws + 301989888LL);
    float*    kvb  = (float*)(ws + 436207616LL);     // [8192][2048]

    // 1. splits (fp32 -> hi/lo fp16)
    split_f32<<<2048, 256, 0, stream>>>(x,  A2x, 8192);
    split_f32<<<2048, 256, 0, stream>>>(Wq, B2q, 4096);
    split_f32<<<1024, 256, 0, stream>>>(Wk, B2kv, 1024);
    split_f32<<<1024, 256, 0, stream>>>(Wv, B2v, 1024);
    split_f32<<<2048, 256, 0, stream>>>(Wo, B2o, 4096);

    // 2. projections
    gemm_split3_8w<<<512, 512, 0, stream>>>(A2x, B2q,  qb,  bq, nullptr, 4096);
    gemm_split3_8w<<<256, 512, 0, stream>>>(A2x, B2kv, kvb, bk, bv,      2048);

    // 3. per-token attention -> split fp16 into A2x
    attn_token<<<8192, 256, 0, stream>>>(qb, kvb, A2x);

    // 4. output projection
    gemm_split3_8w<<<512, 512, 0, stream>>>(A2x, B2o, out, bo, nullptr, 4096);
}

// Round 4
// 2432.269 us; speedup vs baseline: 1.2543x; 1.0812x over previous
//
#include <hip/hip_runtime.h>
#include <hip/hip_bf16.h>

// ---------------------------------------------------------------------------
// MLXAttention on MI355X — fp32-accurate via fp16 hi/lo split GEMMs.
//
//   1. split x -> A2x [8192 x 8192] fp16 (cols 0..4095 hi, 4096.. lo);
//      split Wq/Wk/Wv/Wo likewise.
//   2. q = A2x (*) B2q + bq ; kv = A2x (*) [B2k;B2v] + [bk;bv]  (fused N=2048)
//      3-product MFMA GEMM (hi*hi + hi*lo + lo*hi), 256x256 tile, 8 waves,
//      3-phase K-step, COUNTED-vmcnt double buffer (T4: never drain in-loop).
//   3. per-token attention (softmax over 8 kv heads == reference's 32-way
//      over x4-tiled duplicates) -> split fp16 into A2x (reused).
//   4. out = A2attn (*) B2o + bo.
//
// GEMM K-step (BK=32), dbuf CUR/NXT, stage groups by deadline:
//   G1 = {Ahi(2), Bhi(2)}  needed at P0   issued prev step P0
//   G2 = {Blo(2)}          needed at P1   issued prev step P1
//   G3 = {Alo(2)}          needed at P2   issued prev step P2
// In-order VMEM retirement => exact counted waits (8 outstanding max):
//   P0: vmcnt(4) | bar | ds_read bh,ah | issue G1(NXT) | prio1 32 MFMA hh
//   P1: vmcnt(6) | bar | ds_read bl    | issue G2(NXT) | prio1 32 MFMA hl
//   P2: vmcnt(6) | bar | ds_read al    | issue G3(NXT) | prio1 32 MFMA lh
// Single barrier/phase is safe: each phase's ds_reads complete (lgkmcnt
// before MFMA) before the wave reaches the NEXT phase's barrier, and DMA
// writes into a region are issued only after that barrier.
// LDS swizzle (0 conflicts, verified r2): linear gload_lds dest + global src
// col16' = (lane&3)^((lane>>3)&3); ds_read col16' = (lane>>4)^((lane>>1)&3).
// C stores are non-temporal: keeps A (128 MB) L3-resident across bcol sweeps.
//
// ws layout (bytes):            offset        size
//   A2x / A2attn (fp16)         0             134,217,728
//   B2q (fp16)                  134,217,728    67,108,864
//   B2k|B2v (fp16, contiguous)  201,326,592    33,554,432
//   B2o (fp16)                  234,881,024    67,108,864
//   q (f32)                     301,989,888   134,217,728
//   kv (f32) [8192][2048]       436,207,616    67,108,864
//   total                       503,316,480  (~480 MiB)
// ---------------------------------------------------------------------------

typedef _Float16 half8 __attribute__((ext_vector_type(8)));
typedef _Float16 half4v __attribute__((ext_vector_type(4)));
typedef float floatx4 __attribute__((ext_vector_type(4)));

#define K_DIM 4096
#define LDAB 8192   // row stride (halfs) of split matrices
#define BM 256
#define BN 256
#define BK 32
#define NSTEP 128   // K_DIM / BK

__device__ __forceinline__ void gload16(const void* g, void* l) {
    __builtin_amdgcn_global_load_lds((const __attribute__((address_space(1))) void*)g,
                                     (__attribute__((address_space(3))) void*)l,
                                     16, 0, 0);
}

// ---------------------------------------------------------------------------
__global__ __launch_bounds__(256) void split_f32(
    const float* __restrict__ src, _Float16* __restrict__ dst, long long rows) {
    long long n4 = rows * 1024;   // float4 count (4096 cols / 4)
    long long stride = (long long)gridDim.x * blockDim.x;
    for (long long i = (long long)blockIdx.x * blockDim.x + threadIdx.x; i < n4; i += stride) {
        float4 v = ((const float4*)src)[i];
        long long r = i >> 10;
        int c = ((int)(i & 1023)) << 2;
        half4v hi, lo;
        hi[0] = (_Float16)v.x; lo[0] = (_Float16)(v.x - (float)hi[0]);
        hi[1] = (_Float16)v.y; lo[1] = (_Float16)(v.y - (float)hi[1]);
        hi[2] = (_Float16)v.z; lo[2] = (_Float16)(v.z - (float)hi[2]);
        hi[3] = (_Float16)v.w; lo[3] = (_Float16)(v.w - (float)hi[3]);
        *(half4v*)&dst[r * LDAB + c] = hi;
        *(half4v*)&dst[r * LDAB + K_DIM + c] = lo;
    }
}

// ---------------------------------------------------------------------------
// C[M,N] = A2 (*) B2^T + bias, fused 3-product.  1-D grid, nwg % 8 == 0.
// bias1 != nullptr => KV mode: cols >= 1024 use bias1[col-1024].
// ---------------------------------------------------------------------------
__global__ __launch_bounds__(512, 2) void gemm_split3_8w(
    const _Float16* __restrict__ A, const _Float16* __restrict__ B,
    float* __restrict__ C, const float* __restrict__ bias0,
    const float* __restrict__ bias1, int N) {

    __shared__ __attribute__((aligned(16))) _Float16 lA[2][2][BM * BK];
    __shared__ __attribute__((aligned(16))) _Float16 lB[2][2][BN * BK];

    const int tid = threadIdx.x;
    const int lane = tid & 63;
    const int w = tid >> 6;          // wave 0..7
    const int wm = w >> 2;           // 0..1 -> 128-row half
    const int wn = w & 3;            // 0..3 -> 64-col quarter

    // chunked XCD swizzle + brow-major-within-bcol panel order
    const int f = blockIdx.x;
    const int nwg = gridDim.x;
    const int lid = (f & 7) * (nwg >> 3) + (f >> 3);
    const long long brow = (long long)(lid & 31) * BM;   // M/BM == 32 always
    const long long bcol = (long long)(lid >> 5) * BN;

    floatx4 acc[8][4];
#pragma unroll
    for (int m = 0; m < 8; ++m)
#pragma unroll
        for (int n = 0; n < 4; ++n)
            acc[m][n] = (floatx4){0.f, 0.f, 0.f, 0.f};

    // staging: issue i covers rows i*128 + w*16 + (lane>>2); swizzled src col
    const int srow = w * 16 + (lane >> 2);
    const int scol = 8 * ((lane & 3) ^ ((lane >> 3) & 3));
    const _Float16* Asrc = A + (brow + srow) * (long long)LDAB + scol;
    const _Float16* Bsrc = B + (bcol + srow) * (long long)LDAB + scol;

    const int rA = lane & 15;
    const int kcs = 8 * ((lane >> 4) ^ ((lane >> 1) & 3));   // swizzled read col

    // stage groups by deadline (issue order fixed: G1, G2, G3)
    auto stageG1 = [&](int NXT, int ktn) {   // Ahi + Bhi (4 loads)
        gload16(Asrc + ktn, &lA[NXT][0][w * 512]);
        gload16(Asrc + 128 * (long long)LDAB + ktn, &lA[NXT][0][4096 + w * 512]);
        gload16(Bsrc + ktn, &lB[NXT][0][w * 512]);
        gload16(Bsrc + 128 * (long long)LDAB + ktn, &lB[NXT][0][4096 + w * 512]);
    };
    auto stageG2 = [&](int NXT, int ktn) {   // Blo (2 loads)
        gload16(Bsrc + K_DIM + ktn, &lB[NXT][1][w * 512]);
        gload16(Bsrc + 128 * (long long)LDAB + K_DIM + ktn, &lB[NXT][1][4096 + w * 512]);
    };
    auto stageG3 = [&](int NXT, int ktn) {   // Alo (2 loads)
        gload16(Asrc + K_DIM + ktn, &lA[NXT][1][w * 512]);
        gload16(Asrc + 128 * (long long)LDAB + K_DIM + ktn, &lA[NXT][1][4096 + w * 512]);
    };

    // prologue: fill buffer 0 (8 outstanding, no drain)
    stageG1(0, 0);
    stageG2(0, 0);
    stageG3(0, 0);

    auto step = [&](int CUR, int NXT, int ktn) {
        half8 ah[8], bh[4];
        // ---- P0: hi*hi  (need G1(CUR): oldest 4 of 8 outstanding) ----
        asm volatile("s_waitcnt vmcnt(4)" ::: "memory");
        __builtin_amdgcn_s_barrier();
#pragma unroll
        for (int n = 0; n < 4; ++n)
            bh[n] = *(const half8*)&lB[CUR][0][(wn * 64 + n * 16 + rA) * BK + kcs];
#pragma unroll
        for (int m = 0; m < 8; ++m)
            ah[m] = *(const half8*)&lA[CUR][0][(wm * 128 + m * 16 + rA) * BK + kcs];
        stageG1(NXT, ktn);
        __builtin_amdgcn_s_setprio(1);
#pragma unroll
        for (int m = 0; m < 8; ++m)
#pragma unroll
            for (int n = 0; n < 4; ++n)
                acc[m][n] = __builtin_amdgcn_mfma_f32_16x16x32_f16(
                    ah[m], bh[n], acc[m][n], 0, 0, 0);
        __builtin_amdgcn_s_setprio(0);
        // ---- P1: hi*lo  (need G2(CUR): remaining after = G3(2)+G1'(4)) ----
        {
            half8 bl[4];
            asm volatile("s_waitcnt vmcnt(6)" ::: "memory");
            __builtin_amdgcn_s_barrier();
#pragma unroll
            for (int n = 0; n < 4; ++n)
                bl[n] = *(const half8*)&lB[CUR][1][(wn * 64 + n * 16 + rA) * BK + kcs];
            stageG2(NXT, ktn);
            __builtin_amdgcn_s_setprio(1);
#pragma unroll
            for (int m = 0; m < 8; ++m)
#pragma unroll
                for (int n = 0; n < 4; ++n)
                    acc[m][n] = __builtin_amdgcn_mfma_f32_16x16x32_f16(
                        ah[m], bl[n], acc[m][n], 0, 0, 0);
            __builtin_amdgcn_s_setprio(0);
        }
        // ---- P2: lo*hi  (need G3(CUR): remaining after = G1'(4)+G2'(2)) ----
        {
            half8 al[8];
            asm volatile("s_waitcnt vmcnt(6)" ::: "memory");
            __builtin_amdgcn_s_barrier();
#pragma unroll
            for (int m = 0; m < 8; ++m)
                al[m] = *(const half8*)&lA[CUR][1][(wm * 128 + m * 16 + rA) * BK + kcs];
            stageG3(NXT, ktn);
            __builtin_amdgcn_s_setprio(1);
#pragma unroll
            for (int m = 0; m < 8; ++m)
#pragma unroll
                for (int n = 0; n < 4; ++n)
                    acc[m][n] = __builtin_amdgcn_mfma_f32_16x16x32_f16(
                        al[m], bh[n], acc[m][n], 0, 0, 0);
            __builtin_amdgcn_s_setprio(0);
        }
    };

    for (int tt = 0; tt < NSTEP; tt += 2) {
        step(0, 1, (tt + 1) * BK);
        step(1, 0, ((tt + 2) & (NSTEP - 1)) * BK);   // wrap: harmless in-bounds prefetch
    }
    asm volatile("s_waitcnt vmcnt(0)" ::: "memory");  // drain leftovers (once)

    // epilogue: C/D layout col = lane&15, row = (lane>>4)*4 + reg.
    // Non-temporal stores: don't let C evict the A-panels from L3.
    const float* bias = (bias1 != nullptr && bcol >= 1024) ? (bias1 - 1024) : bias0;
    const int crow0 = (lane >> 4) * 4;
    const int ccol = lane & 15;
#pragma unroll
    for (int n = 0; n < 4; ++n) {
        long long col = bcol + wn * 64 + n * 16 + ccol;
        float bv_ = bias[col];
#pragma unroll
        for (int m = 0; m < 8; ++m) {
            long long row = brow + wm * 128 + m * 16 + crow0;
            float* cp = C + row * (long long)N + col;
            __builtin_nontemporal_store(acc[m][n][0] + bv_, cp);
            __builtin_nontemporal_store(acc[m][n][1] + bv_, cp + (long long)N);
            __builtin_nontemporal_store(acc[m][n][2] + bv_, cp + 2LL * N);
            __builtin_nontemporal_store(acc[m][n][3] + bv_, cp + 3LL * N);
        }
    }
}

// ---------------------------------------------------------------------------
// Per-token attention. Reference tiles k/v x4 over heads then softmaxes over
// 32 scores; duplicated columns reduce exactly to softmax over 8 kv heads.
// kv: [8192][2048] f32, cols 0..1023 = K (8 heads x 128), 1024.. = V.
// ---------------------------------------------------------------------------
__global__ __launch_bounds__(256) void attn_token(
    const float* __restrict__ q, const float* __restrict__ kv,
    _Float16* __restrict__ out) {

    const int token = blockIdx.x;
    __shared__ float sQ[32 * 128];
    __shared__ float sK[8 * 128];
    __shared__ float sV[8 * 128];
    __shared__ float sP[32 * 8];

    const int t = threadIdx.x;
    {
        const float4* gq = (const float4*)(q + (long long)token * 4096);
        float4* dq = (float4*)sQ;
        dq[t] = gq[t];
        dq[t + 256] = gq[t + 256];
        dq[t + 512] = gq[t + 512];
        dq[t + 768] = gq[t + 768];
        const float4* gkv = (const float4*)(kv + (long long)token * 2048);
        ((float4*)sK)[t] = gkv[t];
        ((float4*)sV)[t] = gkv[t + 256];
    }
    __syncthreads();

    const int h = t >> 3, j = t & 7;
    const float* qr = sQ + h * 128;
    const float* kr = sK + j * 128;
    float s = 0.f;
#pragma unroll
    for (int i = 0; i < 128; i += 4)
        s += qr[i] * kr[i] + qr[i + 1] * kr[i + 1] +
             qr[i + 2] * kr[i + 2] + qr[i + 3] * kr[i + 3];
    s *= 0.08838834764831845f;   // 1/sqrt(128)

    float mx = s;
    mx = fmaxf(mx, __shfl_xor(mx, 1, 8));
    mx = fmaxf(mx, __shfl_xor(mx, 2, 8));
    mx = fmaxf(mx, __shfl_xor(mx, 4, 8));
    float e = expf(s - mx);
    float sum = e;
    sum += __shfl_xor(sum, 1, 8);
    sum += __shfl_xor(sum, 2, 8);
    sum += __shfl_xor(sum, 4, 8);
    sP[t] = e / sum;
    __syncthreads();

    float p[8];
#pragma unroll
    for (int jj = 0; jj < 8; ++jj) p[jj] = sP[(t >> 3) * 8 + jj];
    const int d0 = (t & 7) * 16;
    const long long obase = (long long)token * LDAB + (t >> 3) * 128;
#pragma unroll
    for (int dd = 0; dd < 16; ++dd) {
        int d = d0 + dd;
        float a = 0.f;
#pragma unroll
        for (int jj = 0; jj < 8; ++jj) a += p[jj] * sV[jj * 128 + d];
        _Float16 hi = (_Float16)a;
        _Float16 lo = (_Float16)(a - (float)hi);
        out[obase + d] = hi;
        out[obase + K_DIM + d] = lo;
    }
}

// ---------------------------------------------------------------------------
extern "C" void kernel_launch(void* const* d_in, const int* in_sizes, int n_in,
                              void* d_out, int out_size, void* d_ws, size_t ws_size,
                              hipStream_t stream) {
    const float* x  = (const float*)d_in[0];
    const float* Wq = (const float*)d_in[1];
    const float* bq = (const float*)d_in[2];
    const float* Wk = (const float*)d_in[3];
    const float* bk = (const float*)d_in[4];
    const float* Wv = (const float*)d_in[5];
    const float* bv = (const float*)d_in[6];
    const float* Wo = (const float*)d_in[7];
    const float* bo = (const float*)d_in[8];
    float* out = (float*)d_out;

    char* ws = (char*)d_ws;
    _Float16* A2x  = (_Float16*)(ws + 0);            // reused for attn output
    _Float16* B2q  = (_Float16*)(ws + 134217728LL);
    _Float16* B2kv = (_Float16*)(ws + 201326592LL);  // B2k then B2v, contiguous
    _Float16* B2v  = (_Float16*)(ws + 218103808LL);
    _Float16* B2o  = (_Float16*)(ws + 234881024LL);
    float*    qb   = (float*)(ws + 301989888LL);
    float*    kvb  = (float*)(ws + 436207616LL);     // [8192][2048]

    // 1. splits (fp32 -> hi/lo fp16)
    split_f32<<<2048, 256, 0, stream>>>(x,  A2x, 8192);
    split_f32<<<2048, 256, 0, stream>>>(Wq, B2q, 4096);
    split_f32<<<1024, 256, 0, stream>>>(Wk, B2kv, 1024);
    split_f32<<<1024, 256, 0, stream>>>(Wv, B2v, 1024);
    split_f32<<<2048, 256, 0, stream>>>(Wo, B2o, 4096);

    // 2. projections
    gemm_split3_8w<<<512, 512, 0, stream>>>(A2x, B2q,  qb,  bq, nullptr, 4096);
    gemm_split3_8w<<<256, 512, 0, stream>>>(A2x, B2kv, kvb, bk, bv,      2048);

    // 3. per-token attention -> split fp16 into A2x
    attn_token<<<8192, 256, 0, stream>>>(qb, kvb, A2x);

    // 4. output projection
    gemm_split3_8w<<<512, 512, 0, stream>>>(A2x, B2o, out, bo, nullptr, 4096);
}